// Round 8
// baseline (276.328 us; speedup 1.0000x reference)
//
#include <hip/hip_runtime.h>
#include <hip/hip_bf16.h>

#define NN 384
#define DD 128
#define MM (NN*NN)   // 147456 rows

typedef __attribute__((ext_vector_type(8))) short short8;
typedef __attribute__((ext_vector_type(4))) float f32x4;

__device__ __forceinline__ unsigned short f2bf(float f){
  unsigned u = __float_as_uint(f);
  u += 0x7fffu + ((u >> 16) & 1u);      // RNE
  return (unsigned short)(u >> 16);
}
__device__ __forceinline__ float bf2f(unsigned short u){
  return __uint_as_float(((unsigned)u) << 16);
}
__device__ __forceinline__ float sigm(float x){
  return 1.0f / (1.0f + __expf(-x));
}
__device__ __forceinline__ unsigned cvtpk(float lo, float hi){
  unsigned r;
  asm("v_cvt_pk_bf16_f32 %0, %1, %2" : "=v"(r) : "v"(lo), "v"(hi));
  return r;
}
__device__ __forceinline__ f32x4 mfma16(short8 a, short8 b, f32x4 c){
  return __builtin_amdgcn_mfma_f32_16x16x32_bf16(a, b, c, 0, 0, 0);
}
// async global->LDS, 16B/lane; LDS base wave-uniform (HW adds lane*16)
__device__ __forceinline__ void gll16(const void* g, void* l){
  __builtin_amdgcn_global_load_lds(
      (const __attribute__((address_space(1))) unsigned int*)g,
      (__attribute__((address_space(3))) unsigned int*)l, 16, 0, 0);
}
// raw barrier: drain LDS ops (cross-wave visibility) but leave global loads
// in flight (register scoreboard covers their consumers).
__device__ __forceinline__ void barL(){
  asm volatile("s_waitcnt lgkmcnt(0)" ::: "memory");
  __builtin_amdgcn_s_barrier();
}

// ---------------------------------------------------------------------------
// k_prep: Wcat_t[n][k] bf16 = [Wl|Wlg|Wr|Wrg|Wog]^T (n in [0,640)); Wot = Wo^T.
__global__ void k_prep(const float* __restrict__ Wl, const float* __restrict__ Wlg,
                       const float* __restrict__ Wr, const float* __restrict__ Wrg,
                       const float* __restrict__ Wog, const float* __restrict__ Wo,
                       unsigned short* __restrict__ Wcat, unsigned short* __restrict__ Wot){
  int n = blockIdx.x;           // 0..767
  if(n < 640){
    const float* src; int col;
    if(n < 128){ src = Wl;  col = n; }
    else if(n < 256){ src = Wlg; col = n-128; }
    else if(n < 384){ src = Wr;  col = n-256; }
    else if(n < 512){ src = Wrg; col = n-384; }
    else            { src = Wog; col = n-512; }
    for(int k = threadIdx.x; k < 128; k += 64)
      Wcat[n*128 + k] = f2bf(src[k*128 + col]);
  } else {
    int c = n - 640;
    for(int k = threadIdx.x; k < 128; k += 64)
      Wot[c*128 + k] = f2bf(Wo[k*128 + c]);
  }
}

// ---------------------------------------------------------------------------
// k_ln_x: layernorm rows of x (fp32) -> xn bf16.  One wave per row.
__global__ __launch_bounds__(256) void k_ln_x(const float* __restrict__ x,
    const float* __restrict__ na, const float* __restrict__ nb,
    unsigned short* __restrict__ xn){
  int wid = threadIdx.x >> 6, lane = threadIdx.x & 63;
  long r = (long)blockIdx.x*4 + wid;
  float2 v = *(const float2*)(x + r*DD + lane*2);
  float s  = v.x + v.y;
  float sq = v.x*v.x + v.y*v.y;
  #pragma unroll
  for(int m = 32; m >= 1; m >>= 1){ s += __shfl_xor(s, m); sq += __shfl_xor(sq, m); }
  float mean = s  * (1.0f/128.0f);
  float var  = sq * (1.0f/128.0f) - mean*mean;
  float rstd = rsqrtf(var + 1e-5f);
  float2 a = *(const float2*)(na + lane*2);
  float2 b = *(const float2*)(nb + lane*2);
  unsigned pk = (unsigned)f2bf(a.x*(v.x-mean)*rstd + b.x)
              | ((unsigned)f2bf(a.y*(v.y-mean)*rstd + b.y) << 16);
  *(unsigned*)(xn + r*DD + lane*2) = pk;
}

// ---------------------------------------------------------------------------
// k_proj: persistent L/R projection (unchanged).
__global__ __launch_bounds__(256, 4) void k_proj(
    const unsigned short* __restrict__ xn, const unsigned short* __restrict__ Wcat,
    const float* __restrict__ bl, const float* __restrict__ blg,
    const float* __restrict__ br, const float* __restrict__ brg,
    unsigned short* __restrict__ Lt, unsigned short* __restrict__ Rt){
  __shared__ char lds[2][16384];
  const int tid = threadIdx.x;
  const int wid = tid >> 6, lane = tid & 63;
  const int lrow = lane & 15, lgrp = lane >> 4;
  const int b = blockIdx.x;            // 1152 = 4*288
  const int f = b / 288;               // d-quarter
  const int w = b % 288;

  const int ws = wid >> 1;             // 0=L 1=R
  const int wd = wid & 1;              // d-16-half of quarter
  const int d  = f*32 + wd*16 + lrow;

  short8 bv[4], bg[4];
  #pragma unroll
  for(int ks = 0; ks < 4; ++ks){
    bv[ks] = *(const short8*)(Wcat + (ws*256 + d)*DD + ks*32 + lgrp*8);
    bg[ks] = *(const short8*)(Wcat + (ws*256 + 128 + d)*DD + ks*32 + lgrp*8);
  }
  const float b0v = (ws ? br  : bl )[d];
  const float b1v = (ws ? brg : blg)[d];
  const float sc  = ws ? 1.0f : (1.0f/384.0f);   // fold einsum 1/n into Lt
  unsigned short* const base = (ws ? Rt : Lt) + (long)d*MM;

  auto stage = [&](int buf, int v){
    int j = v/6, kb = v%6;
    int rsub = lane >> 4, c = lane & 15;
    #pragma unroll
    for(int p = 0; p < 4; ++p){
      int r0 = p*16 + wid*4;
      int r = r0 + rsub;
      gll16(xn + ((long)(kb*64 + r)*NN + j)*DD + (c ^ (r & 7))*8, &lds[buf][r0*256]);
    }
  };

  stage(0, w*8);
  __syncthreads();
  int cur = 0;
  for(int i = 0; i < 8; ++i){
    int v = w*8 + i;
    if(i < 7) stage(cur^1, v+1);       // prefetch flies over compute+epilogue

    f32x4 zero = {0.f,0.f,0.f,0.f};
    f32x4 acc[4][2];
    #pragma unroll
    for(int a1=0;a1<4;++a1){ acc[a1][0] = zero; acc[a1][1] = zero; }

    #pragma unroll
    for(int ks = 0; ks < 4; ++ks){
      #pragma unroll
      for(int fr = 0; fr < 4; ++fr){
        int r = fr*16 + lrow;
        short8 af = *(const short8*)(&lds[cur][r*256 + (((ks*4+lgrp)*16) ^ ((r&7)<<4))]);
        acc[fr][0] = mfma16(af, bv[ks], acc[fr][0]);
        acc[fr][1] = mfma16(af, bg[ks], acc[fr][1]);
      }
    }

    int j = v/6, kb = v%6;
    unsigned short* dst = base + (long)j*NN + kb*64;
    #pragma unroll
    for(int fr = 0; fr < 4; ++fr){
      float v0 = (acc[fr][0][0] + b0v)*sigm(acc[fr][1][0] + b1v)*sc;
      float v1 = (acc[fr][0][1] + b0v)*sigm(acc[fr][1][1] + b1v)*sc;
      float v2 = (acc[fr][0][2] + b0v)*sigm(acc[fr][1][2] + b1v)*sc;
      float v3 = (acc[fr][0][3] + b0v)*sigm(acc[fr][1][3] + b1v)*sc;
      uint2 pk; pk.x = cvtpk(v0, v1); pk.y = cvtpk(v2, v3);
      *(uint2*)(dst + fr*16 + lgrp*4) = pk;
    }
    __syncthreads();                   // prefetch landed; buffers swap
    cur ^= 1;
  }
}

// ---------------------------------------------------------------------------
// k_einsum: unchanged.
__global__ __launch_bounds__(256) void k_einsum(
    const unsigned short* __restrict__ Rt, const unsigned short* __restrict__ Lt,
    unsigned short* __restrict__ mid){
  __shared__ char lds[65536];
  const int b = blockIdx.x;              // 1152 = 8 * 144
  const int xcd = b & 7, slot = b >> 3;
  const int d = (slot/9)*8 + xcd;
  const int t = slot % 9;
  const int it = t/3, jt = t%3;
  const int i0 = it*128, j0 = jt*128;
  const unsigned short* Abase = Lt + (long)d*MM;   // j-rows
  const unsigned short* Bbase = Rt + (long)d*MM;   // i-rows
  const int wid = threadIdx.x >> 6, lane = threadIdx.x & 63;
  const int wr = wid >> 1, wc = wid & 1;
  const int lrow = lane & 15, lgrp = lane >> 4;

  auto stage = [&](int buf, int kt){
    int k = kt*64;
    int c = lane & 7;
    #pragma unroll
    for(int t8 = 0; t8 < 8; ++t8){
      int rr = wid*64 + t8*8 + (lane >> 3);   // 0..255 (first 128 = A rows)
      int r = rr & 127;
      const unsigned short* src = (rr < 128) ? (Abase + (long)(j0+r)*NN + k)
                                             : (Bbase + (long)(i0+r)*NN + k);
      gll16(src + (c ^ (r & 7))*8, &lds[buf*32768 + (wid*64 + t8*8)*128]);
    }
  };

  f32x4 zero = {0.f,0.f,0.f,0.f};
  f32x4 acc[4][4];                       // [fj][fi]
  #pragma unroll
  for(int a1 = 0; a1 < 4; ++a1)
    #pragma unroll
    for(int a2 = 0; a2 < 4; ++a2) acc[a1][a2] = zero;

  stage(0, 0);
  __syncthreads();
  for(int kt = 0; kt < 6; ++kt){
    int cur = kt & 1;
    if(kt < 5) stage(cur ^ 1, kt + 1);
    const int base = cur*32768;
    #pragma unroll
    for(int ks = 0; ks < 2; ++ks){
      short8 af[4], bf[4];
      #pragma unroll
      for(int f = 0; f < 4; ++f){
        int rj = wr*64 + f*16 + lrow;
        af[f] = *(const short8*)(&lds[base + rj*128 + (((ks*4+lgrp)*16) ^ ((rj & 7) << 4))]);
        int ri = wc*64 + f*16 + lrow;
        bf[f] = *(const short8*)(&lds[base + 16384 + ri*128 + (((ks*4+lgrp)*16) ^ ((ri & 7) << 4))]);
      }
      #pragma unroll
      for(int fj = 0; fj < 4; ++fj)
        #pragma unroll
        for(int fi = 0; fi < 4; ++fi)
          acc[fj][fi] = mfma16(af[fj], bf[fi], acc[fj][fi]);
    }
    __syncthreads();
  }

  #pragma unroll
  for(int fj = 0; fj < 4; ++fj){
    int j = j0 + wr*64 + fj*16 + lgrp*4;
    #pragma unroll
    for(int fi = 0; fi < 4; ++fi){
      int i = i0 + wc*64 + fi*16 + lrow;
      uint2 pk;
      pk.x = cvtpk(acc[fj][fi][0], acc[fj][fi][1]);
      pk.y = cvtpk(acc[fj][fi][2], acc[fj][fi][3]);
      *(uint2*)(mid + (long)d*MM + (long)i*NN + j) = pk;
    }
  }
}

// ---------------------------------------------------------------------------
// k_final v4: 1152 blocks x 2 units (unit = (i, 64-wide j strip)), 21KB LDS,
//  4 blocks/CU. Single 16KB X buffer lives xn -> gate -> val (in-place).
//  LN stats computed from mid-gather REGISTERS (thread (jp,dr) owns d=dr*8..+7
//  x 4 j) via shfl + 2KB wave-partials. Raw lgkm-only barriers keep next
//  unit's xn/mid register-prefetch in flight. Out-proj: A=val rows -> D rows=j,
//  64B-coalesced 4B stores (one wave owns whole rows).
__global__ __launch_bounds__(256, 4) void k_final(
    const unsigned short* __restrict__ mid, const unsigned short* __restrict__ xn,
    const unsigned short* __restrict__ Wcat,
    const float* __restrict__ bog,
    const float* __restrict__ ona, const float* __restrict__ onb,
    const unsigned short* __restrict__ Wot, const float* __restrict__ bo,
    float* __restrict__ out){
  __shared__ char Xb[16384];             // xn -> gate -> val
  __shared__ float4 wavep[128];          // [wave][16 jp][2] = 2KB LN partials
  __shared__ float2 statB[64];           // mean,rstd per j
  __shared__ float clds[512];            // [ona|onb|bog|bo]
  const int tid = threadIdx.x;
  const int wid = tid >> 6, lane = tid & 63;
  const int lrow = lane & 15, lgrp = lane >> 4;
  const int jp = tid & 15, dr = tid >> 4;     // mid ownership: 4 j x d=dr*8..+7
  const int xr = tid >> 2, xq = tid & 3;      // xn staging: row xr, 4 chunks

  const int u0 = blockIdx.x * 2;

  short8 xnA[4], xnB[4];
  uint2  mA[8], mB[8];

  auto ldxn = [&](short8 (&r)[4], int u){
    int i_ = u/6; long base = ((long)i_*NN + (u%6)*64 + xr)*DD;
    #pragma unroll
    for(int p = 0; p < 4; ++p)
      r[p] = *(const short8*)(xn + base + (p*4 + xq)*8);
  };
  auto ldmid = [&](uint2 (&r)[8], int u){
    int i_ = u/6; long base = (long)i_*NN + (u%6)*64 + jp*4;
    #pragma unroll
    for(int p = 0; p < 8; ++p)
      r[p] = *(const uint2*)(mid + (long)(dr*8 + p)*MM + base);
  };
  auto wrxn = [&](short8 (&r)[4]){
    #pragma unroll
    for(int p = 0; p < 4; ++p)
      *(short8*)(&Xb[xr*256 + (((p*4 + xq)*16) ^ ((xr & 7) << 4))]) = r[p];
  };

  // prologue
  ldxn(xnA, u0);
  ldmid(mA, u0);
  if(tid < 128){
    clds[tid]       = ona[tid];
    clds[128 + tid] = onb[tid];
    clds[256 + tid] = bog[tid];
    clds[384 + tid] = bo[tid];
  }
  wrxn(xnA);
  __syncthreads();

  auto unit = [&](int u, uint2 (&mc)[8], short8 (&xnn)[4], uint2 (&mn)[8],
                  bool hasNext){
    const int iU = u/6, jU = (u%6)*64;

    if(hasNext){ ldxn(xnn, u+1); ldmid(mn, u+1); }   // prefetch (regs)

    // ---- P1: gate MFMA (A = Wog^T cols -> D rows = c) + LN partials
    f32x4 accg[2][4];
    #pragma unroll
    for(int cf = 0; cf < 2; ++cf){
      int c0 = wid*32 + cf*16 + lgrp*4;
      float4 b4 = *(const float4*)&clds[256 + c0];
      #pragma unroll
      for(int mf = 0; mf < 4; ++mf) accg[cf][mf] = (f32x4){b4.x, b4.y, b4.z, b4.w};
    }
    #pragma unroll
    for(int ks = 0; ks < 4; ++ks){
      short8 ag[2];
      #pragma unroll
      for(int cf = 0; cf < 2; ++cf)
        ag[cf] = *(const short8*)(Wcat + (512 + wid*32 + cf*16 + lrow)*DD + ks*32 + lgrp*8);
      short8 bx[4];
      #pragma unroll
      for(int mf = 0; mf < 4; ++mf){
        int r = mf*16 + lrow;
        bx[mf] = *(const short8*)(&Xb[r*256 + (((ks*4+lgrp)*16) ^ ((r&7)<<4))]);
      }
      #pragma unroll
      for(int cf = 0; cf < 2; ++cf)
        #pragma unroll
        for(int mf = 0; mf < 4; ++mf)
          accg[cf][mf] = mfma16(ag[cf], bx[mf], accg[cf][mf]);
    }
    { // LN partials from regs: sum over this thread's 8 d per j
      float s0=0,s1=0,s2=0,s3=0, q0=0,q1=0,q2=0,q3=0;
      #pragma unroll
      for(int p = 0; p < 8; ++p){
        float v0 = bf2f((unsigned short)(mc[p].x & 0xffffu));
        float v1 = bf2f((unsigned short)(mc[p].x >> 16));
        float v2 = bf2f((unsigned short)(mc[p].y & 0xffffu));
        float v3 = bf2f((unsigned short)(mc[p].y >> 16));
        s0 += v0; q0 += v0*v0;  s1 += v1; q1 += v1*v1;
        s2 += v2; q2 += v2*v2;  s3 += v3; q3 += v3*v3;
      }
      #pragma unroll
      for(int m = 16; m <= 32; m <<= 1){
        s0 += __shfl_xor(s0,m); q0 += __shfl_xor(q0,m);
        s1 += __shfl_xor(s1,m); q1 += __shfl_xor(q1,m);
        s2 += __shfl_xor(s2,m); q2 += __shfl_xor(q2,m);
        s3 += __shfl_xor(s3,m); q3 += __shfl_xor(q3,m);
      }
      if(lane < 16){
        wavep[(wid*16 + lane)*2 + 0] = (float4){s0, q0, s1, q1};
        wavep[(wid*16 + lane)*2 + 1] = (float4){s2, q2, s3, q3};
      }
    }
    barL();                                    // B1

    // ---- P2: gate -> Xb (in place over xn), leaders compute mean/rstd
    #pragma unroll
    for(int cf = 0; cf < 2; ++cf){
      int c0 = wid*32 + cf*16 + lgrp*4;
      #pragma unroll
      for(int mf = 0; mf < 4; ++mf){
        int j = mf*16 + lrow;
        uint2 pk;
        pk.x = cvtpk(sigm(accg[cf][mf][0]), sigm(accg[cf][mf][1]));
        pk.y = cvtpk(sigm(accg[cf][mf][2]), sigm(accg[cf][mf][3]));
        *(uint2*)(&Xb[j*256 + ((c0*2) ^ ((j&7)<<4))]) = pk;
      }
    }
    if(tid < 64){
      int jpp = tid >> 2, jjj = tid & 3;
      float s = 0.f, q = 0.f;
      #pragma unroll
      for(int w = 0; w < 4; ++w){
        float4 f = wavep[(w*16 + jpp)*2 + (jjj >> 1)];
        if(jjj & 1){ s += f.z; q += f.w; } else { s += f.x; q += f.y; }
      }
      float mean = s*(1.f/128.f);
      float var  = q*(1.f/128.f) - mean*mean;
      statB[tid] = (float2){mean, rsqrtf(var + 1e-5f)};
    }
    barL();                                    // B2

    // ---- P3: owners: val = LN(mid)*gate, in place
    {
      float4 a0 = *(const float4*)&clds[dr*8];
      float4 a1 = *(const float4*)&clds[dr*8 + 4];
      float4 b0 = *(const float4*)&clds[128 + dr*8];
      float4 b1 = *(const float4*)&clds[128 + dr*8 + 4];
      float av[8] = {a0.x,a0.y,a0.z,a0.w,a1.x,a1.y,a1.z,a1.w};
      float bv[8] = {b0.x,b0.y,b0.z,b0.w,b1.x,b1.y,b1.z,b1.w};
      #pragma unroll
      for(int jj = 0; jj < 4; ++jj){
        int j = jp*4 + jj;
        float2 mr = statB[j];
        char* gp = &Xb[j*256 + ((dr*16) ^ ((j&7)<<4))];
        short8 g8 = *(const short8*)gp;
        float vv[8];
        #pragma unroll
        for(int p = 0; p < 8; ++p){
          unsigned w = (jj & 1) ? ((jj & 2) ? (mc[p].y >> 16) : (mc[p].x >> 16))
                                : ((jj & 2) ? (mc[p].y & 0xffffu) : (mc[p].x & 0xffffu));
          float m = bf2f((unsigned short)w);
          float g = bf2f((unsigned short)g8[p]);
          vv[p] = (av[p]*(m - mr.x)*mr.y + bv[p]) * g;
        }
        short8 o;
        #pragma unroll
        for(int p = 0; p < 4; ++p){
          unsigned pk = cvtpk(vv[p*2], vv[p*2+1]);
          o[p*2] = (short)(pk & 0xffffu); o[p*2+1] = (short)(pk >> 16);
        }
        *(short8*)gp = o;
      }
    }
    barL();                                    // B3

    // ---- P4: out MFMA (A = val rows -> D rows = j), coalesced 4B stores
    {
      f32x4 acc[8];
      #pragma unroll
      for(int fc = 0; fc < 8; ++fc){
        float bb = clds[384 + fc*16 + lrow];
        acc[fc] = (f32x4){bb, bb, bb, bb};
      }
      #pragma unroll
      for(int ks = 0; ks < 4; ++ks){
        int r = wid*16 + lrow;
        short8 af = *(const short8*)(&Xb[r*256 + (((ks*4+lgrp)*16) ^ ((r&7)<<4))]);
        #pragma unroll
        for(int fc = 0; fc < 8; ++fc){
          short8 bw = *(const short8*)(Wot + (fc*16 + lrow)*DD + ks*32 + lgrp*8);
          acc[fc] = mfma16(af, bw, acc[fc]);
        }
      }
      #pragma unroll
      for(int fc = 0; fc < 8; ++fc){
        int c = fc*16 + lrow;
        #pragma unroll
        for(int q = 0; q < 4; ++q){
          int jl = wid*16 + lgrp*4 + q;
          out[((long)iU*NN + jU + jl)*DD + c] = acc[fc][q];
        }
      }
    }
    barL();                                    // B4: val reads done

    if(hasNext){
      wrxn(xnn);                               // next unit's xn -> Xb
      barL();                                  // visible to all waves
    }
  };

  unit(u0,     mA, xnB, mB, true);
  unit(u0 + 1, mB, xnA, mA, false);
}

// ---------------------------------------------------------------------------
extern "C" void kernel_launch(void* const* d_in, const int* in_sizes, int n_in,
                              void* d_out, int out_size, void* d_ws, size_t ws_size,
                              hipStream_t stream){
  const float* x   = (const float*)d_in[0];
  const float* na  = (const float*)d_in[1];
  const float* nb  = (const float*)d_in[2];
  const float* Wl  = (const float*)d_in[3];
  const float* bl  = (const float*)d_in[4];
  const float* Wr  = (const float*)d_in[5];
  const float* br  = (const float*)d_in[6];
  const float* Wlg = (const float*)d_in[7];
  const float* blg = (const float*)d_in[8];
  const float* Wrg = (const float*)d_in[9];
  const float* brg = (const float*)d_in[10];
  const float* Wog = (const float*)d_in[11];
  const float* bog = (const float*)d_in[12];
  const float* ona = (const float*)d_in[13];
  const float* onb = (const float*)d_in[14];
  const float* Wo  = (const float*)d_in[15];
  const float* bo  = (const float*)d_in[16];
  float* out = (float*)d_out;

  char* ws = (char*)d_ws;
  const size_t SZ = (size_t)MM*DD*2;                    // 37.75 MB
  unsigned short* xn   = (unsigned short*)(ws);         // LIVE until k_final
  unsigned short* Lt   = (unsigned short*)(ws + SZ);
  unsigned short* Rt   = (unsigned short*)(ws + 2*SZ);
  unsigned short* mid  = (unsigned short*)(ws + 3*SZ);
  unsigned short* Wcat = (unsigned short*)(ws + 4*SZ);
  unsigned short* Wot  = (unsigned short*)(ws + 4*SZ + (size_t)640*128*2);

  k_prep  <<<768, 64, 0, stream>>>(Wl, Wlg, Wr, Wrg, Wog, Wo, Wcat, Wot);
  k_ln_x  <<<MM/4, 256, 0, stream>>>(x, na, nb, xn);
  k_proj  <<<1152, 256, 0, stream>>>(xn, Wcat, bl, blg, br, brg, Lt, Rt);
  k_einsum<<<1152, 256, 0, stream>>>(Rt, Lt, mid);
  k_final <<<1152, 256, 0, stream>>>(mid, xn, Wcat, bog, ona, onb, Wot, bo, out);
}

// Round 9
// 237.003 us; speedup vs baseline: 1.1659x; 1.1659x over previous
//
#include <hip/hip_runtime.h>
#include <hip/hip_bf16.h>

#define NN 384
#define DD 128
#define MM (NN*NN)   // 147456 rows

typedef __attribute__((ext_vector_type(8))) short short8;
typedef __attribute__((ext_vector_type(4))) float f32x4;

__device__ __forceinline__ unsigned short f2bf(float f){
  unsigned u = __float_as_uint(f);
  u += 0x7fffu + ((u >> 16) & 1u);      // RNE
  return (unsigned short)(u >> 16);
}
__device__ __forceinline__ float bf2f(unsigned short u){
  return __uint_as_float(((unsigned)u) << 16);
}
__device__ __forceinline__ float sigm(float x){
  return 1.0f / (1.0f + __expf(-x));
}
__device__ __forceinline__ unsigned cvtpk(float lo, float hi){
  unsigned r;
  asm("v_cvt_pk_bf16_f32 %0, %1, %2" : "=v"(r) : "v"(lo), "v"(hi));
  return r;
}
__device__ __forceinline__ f32x4 mfma16(short8 a, short8 b, f32x4 c){
  return __builtin_amdgcn_mfma_f32_16x16x32_bf16(a, b, c, 0, 0, 0);
}
// async global->LDS, 16B/lane; LDS base wave-uniform (HW adds lane*16)
__device__ __forceinline__ void gll16(const void* g, void* l){
  __builtin_amdgcn_global_load_lds(
      (const __attribute__((address_space(1))) unsigned int*)g,
      (__attribute__((address_space(3))) unsigned int*)l, 16, 0, 0);
}
// raw barrier: drain LDS ops only; global loads stay in flight
__device__ __forceinline__ void barL(){
  asm volatile("s_waitcnt lgkmcnt(0)" ::: "memory");
  __builtin_amdgcn_s_barrier();
}

// ---------------------------------------------------------------------------
// k_prep: Wcat_t[n][k] bf16 = [Wl|Wlg|Wr|Wrg|Wog]^T (n in [0,640)); Wot = Wo^T.
__global__ void k_prep(const float* __restrict__ Wl, const float* __restrict__ Wlg,
                       const float* __restrict__ Wr, const float* __restrict__ Wrg,
                       const float* __restrict__ Wog, const float* __restrict__ Wo,
                       unsigned short* __restrict__ Wcat, unsigned short* __restrict__ Wot){
  int n = blockIdx.x;           // 0..767
  if(n < 640){
    const float* src; int col;
    if(n < 128){ src = Wl;  col = n; }
    else if(n < 256){ src = Wlg; col = n-128; }
    else if(n < 384){ src = Wr;  col = n-256; }
    else if(n < 512){ src = Wrg; col = n-384; }
    else            { src = Wog; col = n-512; }
    for(int k = threadIdx.x; k < 128; k += 64)
      Wcat[n*128 + k] = f2bf(src[k*128 + col]);
  } else {
    int c = n - 640;
    for(int k = threadIdx.x; k < 128; k += 64)
      Wot[c*128 + k] = f2bf(Wo[k*128 + c]);
  }
}

// ---------------------------------------------------------------------------
// k_ln_x: layernorm rows of x (fp32) -> xn bf16.  One wave per row.
__global__ __launch_bounds__(256) void k_ln_x(const float* __restrict__ x,
    const float* __restrict__ na, const float* __restrict__ nb,
    unsigned short* __restrict__ xn){
  int wid = threadIdx.x >> 6, lane = threadIdx.x & 63;
  long r = (long)blockIdx.x*4 + wid;
  float2 v = *(const float2*)(x + r*DD + lane*2);
  float s  = v.x + v.y;
  float sq = v.x*v.x + v.y*v.y;
  #pragma unroll
  for(int m = 32; m >= 1; m >>= 1){ s += __shfl_xor(s, m); sq += __shfl_xor(sq, m); }
  float mean = s  * (1.0f/128.0f);
  float var  = sq * (1.0f/128.0f) - mean*mean;
  float rstd = rsqrtf(var + 1e-5f);
  float2 a = *(const float2*)(na + lane*2);
  float2 b = *(const float2*)(nb + lane*2);
  unsigned pk = (unsigned)f2bf(a.x*(v.x-mean)*rstd + b.x)
              | ((unsigned)f2bf(a.y*(v.y-mean)*rstd + b.y) << 16);
  *(unsigned*)(xn + r*DD + lane*2) = pk;
}

// ---------------------------------------------------------------------------
// k_proj: persistent L/R projection (unchanged).
__global__ __launch_bounds__(256, 4) void k_proj(
    const unsigned short* __restrict__ xn, const unsigned short* __restrict__ Wcat,
    const float* __restrict__ bl, const float* __restrict__ blg,
    const float* __restrict__ br, const float* __restrict__ brg,
    unsigned short* __restrict__ Lt, unsigned short* __restrict__ Rt){
  __shared__ char lds[2][16384];
  const int tid = threadIdx.x;
  const int wid = tid >> 6, lane = tid & 63;
  const int lrow = lane & 15, lgrp = lane >> 4;
  const int b = blockIdx.x;            // 1152 = 4*288
  const int f = b / 288;               // d-quarter
  const int w = b % 288;

  const int ws = wid >> 1;             // 0=L 1=R
  const int wd = wid & 1;              // d-16-half of quarter
  const int d  = f*32 + wd*16 + lrow;

  short8 bv[4], bg[4];
  #pragma unroll
  for(int ks = 0; ks < 4; ++ks){
    bv[ks] = *(const short8*)(Wcat + (ws*256 + d)*DD + ks*32 + lgrp*8);
    bg[ks] = *(const short8*)(Wcat + (ws*256 + 128 + d)*DD + ks*32 + lgrp*8);
  }
  const float b0v = (ws ? br  : bl )[d];
  const float b1v = (ws ? brg : blg)[d];
  const float sc  = ws ? 1.0f : (1.0f/384.0f);   // fold einsum 1/n into Lt
  unsigned short* const base = (ws ? Rt : Lt) + (long)d*MM;

  auto stage = [&](int buf, int v){
    int j = v/6, kb = v%6;
    int rsub = lane >> 4, c = lane & 15;
    #pragma unroll
    for(int p = 0; p < 4; ++p){
      int r0 = p*16 + wid*4;
      int r = r0 + rsub;
      gll16(xn + ((long)(kb*64 + r)*NN + j)*DD + (c ^ (r & 7))*8, &lds[buf][r0*256]);
    }
  };

  stage(0, w*8);
  __syncthreads();
  int cur = 0;
  for(int i = 0; i < 8; ++i){
    int v = w*8 + i;
    if(i < 7) stage(cur^1, v+1);       // prefetch flies over compute+epilogue

    f32x4 zero = {0.f,0.f,0.f,0.f};
    f32x4 acc[4][2];
    #pragma unroll
    for(int a1=0;a1<4;++a1){ acc[a1][0] = zero; acc[a1][1] = zero; }

    #pragma unroll
    for(int ks = 0; ks < 4; ++ks){
      #pragma unroll
      for(int fr = 0; fr < 4; ++fr){
        int r = fr*16 + lrow;
        short8 af = *(const short8*)(&lds[cur][r*256 + (((ks*4+lgrp)*16) ^ ((r&7)<<4))]);
        acc[fr][0] = mfma16(af, bv[ks], acc[fr][0]);
        acc[fr][1] = mfma16(af, bg[ks], acc[fr][1]);
      }
    }

    int j = v/6, kb = v%6;
    unsigned short* dst = base + (long)j*NN + kb*64;
    #pragma unroll
    for(int fr = 0; fr < 4; ++fr){
      float v0 = (acc[fr][0][0] + b0v)*sigm(acc[fr][1][0] + b1v)*sc;
      float v1 = (acc[fr][0][1] + b0v)*sigm(acc[fr][1][1] + b1v)*sc;
      float v2 = (acc[fr][0][2] + b0v)*sigm(acc[fr][1][2] + b1v)*sc;
      float v3 = (acc[fr][0][3] + b0v)*sigm(acc[fr][1][3] + b1v)*sc;
      uint2 pk; pk.x = cvtpk(v0, v1); pk.y = cvtpk(v2, v3);
      *(uint2*)(dst + fr*16 + lgrp*4) = pk;
    }
    __syncthreads();                   // prefetch landed; buffers swap
    cur ^= 1;
  }
}

// ---------------------------------------------------------------------------
// k_einsum: unchanged.
__global__ __launch_bounds__(256) void k_einsum(
    const unsigned short* __restrict__ Rt, const unsigned short* __restrict__ Lt,
    unsigned short* __restrict__ mid){
  __shared__ char lds[65536];
  const int b = blockIdx.x;              // 1152 = 8 * 144
  const int xcd = b & 7, slot = b >> 3;
  const int d = (slot/9)*8 + xcd;
  const int t = slot % 9;
  const int it = t/3, jt = t%3;
  const int i0 = it*128, j0 = jt*128;
  const unsigned short* Abase = Lt + (long)d*MM;   // j-rows
  const unsigned short* Bbase = Rt + (long)d*MM;   // i-rows
  const int wid = threadIdx.x >> 6, lane = threadIdx.x & 63;
  const int wr = wid >> 1, wc = wid & 1;
  const int lrow = lane & 15, lgrp = lane >> 4;

  auto stage = [&](int buf, int kt){
    int k = kt*64;
    int c = lane & 7;
    #pragma unroll
    for(int t8 = 0; t8 < 8; ++t8){
      int rr = wid*64 + t8*8 + (lane >> 3);   // 0..255 (first 128 = A rows)
      int r = rr & 127;
      const unsigned short* src = (rr < 128) ? (Abase + (long)(j0+r)*NN + k)
                                             : (Bbase + (long)(i0+r)*NN + k);
      gll16(src + (c ^ (r & 7))*8, &lds[buf*32768 + (wid*64 + t8*8)*128]);
    }
  };

  f32x4 zero = {0.f,0.f,0.f,0.f};
  f32x4 acc[4][4];                       // [fj][fi]
  #pragma unroll
  for(int a1 = 0; a1 < 4; ++a1)
    #pragma unroll
    for(int a2 = 0; a2 < 4; ++a2) acc[a1][a2] = zero;

  stage(0, 0);
  __syncthreads();
  for(int kt = 0; kt < 6; ++kt){
    int cur = kt & 1;
    if(kt < 5) stage(cur ^ 1, kt + 1);
    const int base = cur*32768;
    #pragma unroll
    for(int ks = 0; ks < 2; ++ks){
      short8 af[4], bf[4];
      #pragma unroll
      for(int f = 0; f < 4; ++f){
        int rj = wr*64 + f*16 + lrow;
        af[f] = *(const short8*)(&lds[base + rj*128 + (((ks*4+lgrp)*16) ^ ((rj & 7) << 4))]);
        int ri = wc*64 + f*16 + lrow;
        bf[f] = *(const short8*)(&lds[base + 16384 + ri*128 + (((ks*4+lgrp)*16) ^ ((ri & 7) << 4))]);
      }
      #pragma unroll
      for(int fj = 0; fj < 4; ++fj)
        #pragma unroll
        for(int fi = 0; fi < 4; ++fi)
          acc[fj][fi] = mfma16(af[fj], bf[fi], acc[fj][fi]);
    }
    __syncthreads();
  }

  #pragma unroll
  for(int fj = 0; fj < 4; ++fj){
    int j = j0 + wr*64 + fj*16 + lgrp*4;
    #pragma unroll
    for(int fi = 0; fi < 4; ++fi){
      int i = i0 + wc*64 + fi*16 + lrow;
      uint2 pk;
      pk.x = cvtpk(acc[fj][fi][0], acc[fj][fi][1]);
      pk.y = cvtpk(acc[fj][fi][2], acc[fj][fi][3]);
      *(uint2*)(mid + (long)d*MM + (long)i*NN + j) = pk;
    }
  }
}

// ---------------------------------------------------------------------------
// k_final v5: 1152 blocks x 2 units, macro form (all reg arrays named,
//  compile-time indexed -- no lambda array refs, no scratch).
//  Xb[2]: per-unit xn -> gate -> val buffer; next unit's xn prefetched by
//  gll16 into Xb[nxt] at unit start; mid prefetched into named reg sets
//  mA/mB. LN stats from regs via shfl + 2KB partials. Phase barriers are
//  lgkm-only; one full __syncthreads at unit boundary drains the gll16.
__global__ __launch_bounds__(256, 4) void k_final(
    const unsigned short* __restrict__ mid, const unsigned short* __restrict__ xn,
    const unsigned short* __restrict__ Wcat,
    const float* __restrict__ bog,
    const float* __restrict__ ona, const float* __restrict__ onb,
    const unsigned short* __restrict__ Wot, const float* __restrict__ bo,
    float* __restrict__ out){
  __shared__ char Xb[2][16384];          // xn -> gate -> val (per unit)
  __shared__ float4 wavep[128];          // LN partials
  __shared__ float2 statB[64];           // mean,rstd per j
  __shared__ float clds[512];            // [ona|onb|bog|bo]
  const int tid = threadIdx.x;
  const int wid = tid >> 6, lane = tid & 63;
  const int lrow = lane & 15, lgrp = lane >> 4;
  const int jp = tid & 15, dr = tid >> 4;     // mid ownership: 4 j x d=dr*8..+7
  const int u0 = blockIdx.x * 2;

  uint2 mA[8], mB[8];

#define LDMID(reg, uu) {                                                      \
    int i_ = (uu)/6; long mbase = (long)i_*NN + ((uu)%6)*64 + jp*4;           \
    _Pragma("unroll")                                                         \
    for(int p = 0; p < 8; ++p)                                                \
      reg[p] = *(const uint2*)(mid + (long)(dr*8 + p)*MM + mbase);            \
  }

#define STAGEXN(buf, uu) {                                                    \
    int i_ = (uu)/6, jj_ = ((uu)%6)*64;                                       \
    int rsub = lane >> 4, cc = lane & 15;                                     \
    _Pragma("unroll")                                                         \
    for(int p = 0; p < 4; ++p){                                               \
      int r0 = p*16 + wid*4; int r = r0 + rsub;                               \
      gll16(xn + ((long)i_*NN + jj_ + r)*DD + (cc ^ (r & 7))*8,               \
            &Xb[buf][r0*256]);                                                \
    } }

  // prologue
  STAGEXN(0, u0)
  LDMID(mA, u0)
  if(tid < 128){
    clds[tid]       = ona[tid];
    clds[128 + tid] = onb[tid];
    clds[256 + tid] = bog[tid];
    clds[384 + tid] = bo[tid];
  }
  __syncthreads();

#define UNIT(T, MC, MN, CUR) {                                                \
    const int u_ = u0 + (T);                                                  \
    const int iU = u_/6, jU = (u_%6)*64;                                      \
    if((T) == 0){ STAGEXN((CUR)^1, u_+1) LDMID(MN, u_+1) }                    \
    /* P1: gate MFMA (A=Wog^T cols -> D rows=c) + LN partials from regs */    \
    f32x4 accg[2][4];                                                         \
    _Pragma("unroll")                                                         \
    for(int cf = 0; cf < 2; ++cf){                                            \
      int c0 = wid*32 + cf*16 + lgrp*4;                                       \
      float4 b4 = *(const float4*)&clds[256 + c0];                            \
      _Pragma("unroll")                                                       \
      for(int mf = 0; mf < 4; ++mf)                                           \
        accg[cf][mf] = (f32x4){b4.x, b4.y, b4.z, b4.w};                       \
    }                                                                         \
    _Pragma("unroll")                                                         \
    for(int ks = 0; ks < 4; ++ks){                                            \
      short8 ag0 = *(const short8*)(Wcat + (512 + wid*32 + lrow)*DD + ks*32 + lgrp*8);       \
      short8 ag1 = *(const short8*)(Wcat + (512 + wid*32 + 16 + lrow)*DD + ks*32 + lgrp*8);  \
      short8 bx[4];                                                           \
      _Pragma("unroll")                                                       \
      for(int mf = 0; mf < 4; ++mf){                                          \
        int r = mf*16 + lrow;                                                 \
        bx[mf] = *(const short8*)(&Xb[CUR][r*256 + (((ks*4+lgrp)*16) ^ ((r&7)<<4))]); \
      }                                                                       \
      _Pragma("unroll")                                                       \
      for(int mf = 0; mf < 4; ++mf){                                          \
        accg[0][mf] = mfma16(ag0, bx[mf], accg[0][mf]);                       \
        accg[1][mf] = mfma16(ag1, bx[mf], accg[1][mf]);                       \
      }                                                                       \
    }                                                                         \
    {                                                                         \
      float s0=0,s1=0,s2=0,s3=0, q0=0,q1=0,q2=0,q3=0;                         \
      _Pragma("unroll")                                                       \
      for(int p = 0; p < 8; ++p){                                             \
        float v0 = bf2f((unsigned short)(MC[p].x & 0xffffu));                 \
        float v1 = bf2f((unsigned short)(MC[p].x >> 16));                     \
        float v2 = bf2f((unsigned short)(MC[p].y & 0xffffu));                 \
        float v3 = bf2f((unsigned short)(MC[p].y >> 16));                     \
        s0 += v0; q0 += v0*v0;  s1 += v1; q1 += v1*v1;                        \
        s2 += v2; q2 += v2*v2;  s3 += v3; q3 += v3*v3;                        \
      }                                                                       \
      _Pragma("unroll")                                                       \
      for(int m = 16; m <= 32; m <<= 1){                                      \
        s0 += __shfl_xor(s0,m); q0 += __shfl_xor(q0,m);                       \
        s1 += __shfl_xor(s1,m); q1 += __shfl_xor(q1,m);                       \
        s2 += __shfl_xor(s2,m); q2 += __shfl_xor(q2,m);                       \
        s3 += __shfl_xor(s3,m); q3 += __shfl_xor(q3,m);                       \
      }                                                                       \
      if(lane < 16){                                                          \
        wavep[(wid*16 + lane)*2 + 0] = (float4){s0, q0, s1, q1};              \
        wavep[(wid*16 + lane)*2 + 1] = (float4){s2, q2, s3, q3};              \
      }                                                                       \
    }                                                                         \
    barL();   /* B1 */                                                        \
    /* P2: gate -> Xb[CUR] in place; leaders compute stats */                 \
    _Pragma("unroll")                                                         \
    for(int cf = 0; cf < 2; ++cf){                                            \
      int c0 = wid*32 + cf*16 + lgrp*4;                                       \
      _Pragma("unroll")                                                       \
      for(int mf = 0; mf < 4; ++mf){                                          \
        int j = mf*16 + lrow;                                                 \
        uint2 pk;                                                             \
        pk.x = cvtpk(sigm(accg[cf][mf][0]), sigm(accg[cf][mf][1]));           \
        pk.y = cvtpk(sigm(accg[cf][mf][2]), sigm(accg[cf][mf][3]));           \
        *(uint2*)(&Xb[CUR][j*256 + ((c0*2) ^ ((j&7)<<4))]) = pk;              \
      }                                                                       \
    }                                                                         \
    if(tid < 64){                                                             \
      int jpp = tid >> 2, jjj = tid & 3;                                      \
      float s = 0.f, q = 0.f;                                                 \
      _Pragma("unroll")                                                       \
      for(int w = 0; w < 4; ++w){                                             \
        float4 f = wavep[(w*16 + jpp)*2 + (jjj >> 1)];                        \
        if(jjj & 1){ s += f.z; q += f.w; } else { s += f.x; q += f.y; }       \
      }                                                                       \
      float mean = s*(1.f/128.f);                                             \
      float var  = q*(1.f/128.f) - mean*mean;                                 \
      statB[tid] = (float2){mean, rsqrtf(var + 1e-5f)};                       \
    }                                                                         \
    barL();   /* B2 */                                                        \
    /* P3: val = LN(mid)*gate, in place, from regs */                         \
    {                                                                         \
      float4 a0 = *(const float4*)&clds[dr*8];                                \
      float4 a1 = *(const float4*)&clds[dr*8 + 4];                            \
      float4 b0 = *(const float4*)&clds[128 + dr*8];                          \
      float4 b1 = *(const float4*)&clds[128 + dr*8 + 4];                      \
      float av[8] = {a0.x,a0.y,a0.z,a0.w,a1.x,a1.y,a1.z,a1.w};                \
      float bv[8] = {b0.x,b0.y,b0.z,b0.w,b1.x,b1.y,b1.z,b1.w};                \
      _Pragma("unroll")                                                       \
      for(int jj = 0; jj < 4; ++jj){                                          \
        int j = jp*4 + jj;                                                    \
        float2 mr = statB[j];                                                 \
        char* gp = &Xb[CUR][j*256 + ((dr*16) ^ ((j&7)<<4))];                  \
        short8 g8 = *(const short8*)gp;                                       \
        float vv[8];                                                          \
        _Pragma("unroll")                                                     \
        for(int p = 0; p < 8; ++p){                                           \
          unsigned w = (jj & 1) ? ((jj & 2) ? (MC[p].y >> 16) : (MC[p].x >> 16))              \
                                : ((jj & 2) ? (MC[p].y & 0xffffu) : (MC[p].x & 0xffffu));     \
          float m = bf2f((unsigned short)w);                                  \
          float g = bf2f((unsigned short)g8[p]);                              \
          vv[p] = (av[p]*(m - mr.x)*mr.y + bv[p]) * g;                        \
        }                                                                     \
        short8 o;                                                             \
        _Pragma("unroll")                                                     \
        for(int p = 0; p < 4; ++p){                                           \
          unsigned pk = cvtpk(vv[p*2], vv[p*2+1]);                            \
          o[p*2] = (short)(pk & 0xffffu); o[p*2+1] = (short)(pk >> 16);       \
        }                                                                     \
        *(short8*)gp = o;                                                     \
      }                                                                       \
    }                                                                         \
    barL();   /* B3 */                                                        \
    /* P4: out MFMA (A=val rows -> D rows=j), 64B-coalesced 4B stores */      \
    {                                                                         \
      f32x4 acc[8];                                                           \
      _Pragma("unroll")                                                       \
      for(int fc = 0; fc < 8; ++fc){                                          \
        float bb = clds[384 + fc*16 + lrow];                                  \
        acc[fc] = (f32x4){bb, bb, bb, bb};                                    \
      }                                                                       \
      _Pragma("unroll")                                                       \
      for(int ks = 0; ks < 4; ++ks){                                          \
        int r = wid*16 + lrow;                                                \
        short8 af = *(const short8*)(&Xb[CUR][r*256 + (((ks*4+lgrp)*16) ^ ((r&7)<<4))]); \
        _Pragma("unroll")                                                     \
        for(int fc = 0; fc < 8; ++fc){                                        \
          short8 bw = *(const short8*)(Wot + (fc*16 + lrow)*DD + ks*32 + lgrp*8);        \
          acc[fc] = mfma16(af, bw, acc[fc]);                                  \
        }                                                                     \
      }                                                                       \
      _Pragma("unroll")                                                       \
      for(int fc = 0; fc < 8; ++fc){                                          \
        int c = fc*16 + lrow;                                                 \
        _Pragma("unroll")                                                     \
        for(int q = 0; q < 4; ++q){                                           \
          int jl = wid*16 + lgrp*4 + q;                                       \
          out[((long)iU*NN + jU + jl)*DD + c] = acc[fc][q];                   \
        }                                                                     \
      }                                                                       \
    }                                                                         \
  }

  UNIT(0, mA, mB, 0)
  __syncthreads();                       // drain gll16 for Xb[1] + val reads
  UNIT(1, mB, mA, 1)

#undef UNIT
#undef STAGEXN
#undef LDMID
}

// ---------------------------------------------------------------------------
extern "C" void kernel_launch(void* const* d_in, const int* in_sizes, int n_in,
                              void* d_out, int out_size, void* d_ws, size_t ws_size,
                              hipStream_t stream){
  const float* x   = (const float*)d_in[0];
  const float* na  = (const float*)d_in[1];
  const float* nb  = (const float*)d_in[2];
  const float* Wl  = (const float*)d_in[3];
  const float* bl  = (const float*)d_in[4];
  const float* Wr  = (const float*)d_in[5];
  const float* br  = (const float*)d_in[6];
  const float* Wlg = (const float*)d_in[7];
  const float* blg = (const float*)d_in[8];
  const float* Wrg = (const float*)d_in[9];
  const float* brg = (const float*)d_in[10];
  const float* Wog = (const float*)d_in[11];
  const float* bog = (const float*)d_in[12];
  const float* ona = (const float*)d_in[13];
  const float* onb = (const float*)d_in[14];
  const float* Wo  = (const float*)d_in[15];
  const float* bo  = (const float*)d_in[16];
  float* out = (float*)d_out;

  char* ws = (char*)d_ws;
  const size_t SZ = (size_t)MM*DD*2;                    // 37.75 MB
  unsigned short* xn   = (unsigned short*)(ws);         // LIVE until k_final
  unsigned short* Lt   = (unsigned short*)(ws + SZ);
  unsigned short* Rt   = (unsigned short*)(ws + 2*SZ);
  unsigned short* mid  = (unsigned short*)(ws + 3*SZ);
  unsigned short* Wcat = (unsigned short*)(ws + 4*SZ);
  unsigned short* Wot  = (unsigned short*)(ws + 4*SZ + (size_t)640*128*2);

  k_prep  <<<768, 64, 0, stream>>>(Wl, Wlg, Wr, Wrg, Wog, Wo, Wcat, Wot);
  k_ln_x  <<<MM/4, 256, 0, stream>>>(x, na, nb, xn);
  k_proj  <<<1152, 256, 0, stream>>>(xn, Wcat, bl, blg, br, brg, Lt, Rt);
  k_einsum<<<1152, 256, 0, stream>>>(Rt, Lt, mid);
  k_final <<<1152, 256, 0, stream>>>(mid, xn, Wcat, bog, ona, onb, Wot, bo, out);
}

// Round 10
// 211.406 us; speedup vs baseline: 1.3071x; 1.1211x over previous
//
#include <hip/hip_runtime.h>
#include <hip/hip_bf16.h>

#define NN 384
#define DD 128
#define MM (NN*NN)   // 147456 rows

typedef __attribute__((ext_vector_type(8))) short short8;
typedef __attribute__((ext_vector_type(4))) float f32x4;

__device__ __forceinline__ unsigned short f2bf(float f){
  unsigned u = __float_as_uint(f);
  u += 0x7fffu + ((u >> 16) & 1u);      // RNE
  return (unsigned short)(u >> 16);
}
__device__ __forceinline__ float bf2f(unsigned short u){
  return __uint_as_float(((unsigned)u) << 16);
}
__device__ __forceinline__ float sigm(float x){
  return 1.0f / (1.0f + __expf(-x));
}
__device__ __forceinline__ unsigned cvtpk(float lo, float hi){
  unsigned r;
  asm("v_cvt_pk_bf16_f32 %0, %1, %2" : "=v"(r) : "v"(lo), "v"(hi));
  return r;
}
__device__ __forceinline__ f32x4 mfma16(short8 a, short8 b, f32x4 c){
  return __builtin_amdgcn_mfma_f32_16x16x32_bf16(a, b, c, 0, 0, 0);
}
// async global->LDS, 16B/lane; LDS base wave-uniform (HW adds lane*16)
__device__ __forceinline__ void gll16(const void* g, void* l){
  __builtin_amdgcn_global_load_lds(
      (const __attribute__((address_space(1))) unsigned int*)g,
      (__attribute__((address_space(3))) unsigned int*)l, 16, 0, 0);
}

// ---------------------------------------------------------------------------
// k_prep: Wcat_t[n][k] bf16 = [Wl|Wlg|Wr|Wrg|Wog]^T (n in [0,640)); Wot = Wo^T.
__global__ void k_prep(const float* __restrict__ Wl, const float* __restrict__ Wlg,
                       const float* __restrict__ Wr, const float* __restrict__ Wrg,
                       const float* __restrict__ Wog, const float* __restrict__ Wo,
                       unsigned short* __restrict__ Wcat, unsigned short* __restrict__ Wot){
  int n = blockIdx.x;           // 0..767
  if(n < 640){
    const float* src; int col;
    if(n < 128){ src = Wl;  col = n; }
    else if(n < 256){ src = Wlg; col = n-128; }
    else if(n < 384){ src = Wr;  col = n-256; }
    else if(n < 512){ src = Wrg; col = n-384; }
    else            { src = Wog; col = n-512; }
    for(int k = threadIdx.x; k < 128; k += 64)
      Wcat[n*128 + k] = f2bf(src[k*128 + col]);
  } else {
    int c = n - 640;
    for(int k = threadIdx.x; k < 128; k += 64)
      Wot[c*128 + k] = f2bf(Wo[k*128 + c]);
  }
}

// ---------------------------------------------------------------------------
// k_lng: fused LayerNorm(x) -> xn  AND  gate = sigm(xn @ Wog + bog).
//  1152 blocks x 256 thr, 128 rows each. LN per wave-row (float2/lane),
//  xn row written to global + LDS (swizzled). Then gate MFMA (A=Wog^T rows=c,
//  B=xn rows=m) -> packed 8B stores, PRE-SWIZZLED within each 256B row
//  (byte ^= (row&7)<<4) so k_final can stage linearly and read conflict-free.
__global__ __launch_bounds__(256, 3) void k_lng(
    const float* __restrict__ x, const float* __restrict__ na,
    const float* __restrict__ nb, const unsigned short* __restrict__ Wcat,
    const float* __restrict__ bog,
    unsigned short* __restrict__ xn, unsigned short* __restrict__ gate){
  __shared__ char lds[32768];            // xn tile [128 rows][256B], swizzled
  const int tid = threadIdx.x;
  const int wid = tid >> 6, lane = tid & 63;
  const int lrow = lane & 15, lgrp = lane >> 4;
  const long m0 = (long)blockIdx.x * 128;

  float2 a2 = *(const float2*)(na + lane*2);
  float2 b2 = *(const float2*)(nb + lane*2);

  #pragma unroll 2
  for(int it = 0; it < 32; ++it){
    int r = wid*32 + it;
    float2 v = *(const float2*)(x + (m0 + r)*DD + lane*2);
    float s = v.x + v.y, sq = v.x*v.x + v.y*v.y;
    #pragma unroll
    for(int m = 32; m >= 1; m >>= 1){ s += __shfl_xor(s,m); sq += __shfl_xor(sq,m); }
    float mean = s*(1.f/128.f);
    float var  = sq*(1.f/128.f) - mean*mean;
    float rstd = rsqrtf(var + 1e-5f);
    unsigned pk = cvtpk(a2.x*(v.x-mean)*rstd + b2.x,
                        a2.y*(v.y-mean)*rstd + b2.y);
    *(unsigned*)(xn + (m0+r)*DD + lane*2) = pk;
    *(unsigned*)(&lds[r*256 + ((lane*4) ^ ((r&7)<<4))]) = pk;
  }
  __syncthreads();

  // gate MFMA: wave wid owns 32 c-cols
  f32x4 acc[2][8];                       // [cf][mf]
  #pragma unroll
  for(int cf = 0; cf < 2; ++cf){
    int c0 = wid*32 + cf*16 + lgrp*4;
    float4 b4 = *(const float4*)(bog + c0);
    #pragma unroll
    for(int mf = 0; mf < 8; ++mf) acc[cf][mf] = (f32x4){b4.x,b4.y,b4.z,b4.w};
  }
  #pragma unroll
  for(int ks = 0; ks < 4; ++ks){
    short8 af0 = *(const short8*)(Wcat + (512 + wid*32 + lrow)*DD + ks*32 + lgrp*8);
    short8 af1 = *(const short8*)(Wcat + (512 + wid*32 + 16 + lrow)*DD + ks*32 + lgrp*8);
    #pragma unroll
    for(int mf = 0; mf < 8; ++mf){
      int r = mf*16 + lrow;
      short8 bx = *(const short8*)(&lds[r*256 + (((ks*4+lgrp)*16) ^ ((r&7)<<4))]);
      acc[0][mf] = mfma16(af0, bx, acc[0][mf]);
      acc[1][mf] = mfma16(af1, bx, acc[1][mf]);
    }
  }
  // packed 8B stores, pre-swizzled within the 256B row
  #pragma unroll
  for(int cf = 0; cf < 2; ++cf){
    int c0 = wid*32 + cf*16 + lgrp*4;
    #pragma unroll
    for(int mf = 0; mf < 8; ++mf){
      int rr = mf*16 + lrow;
      uint2 pk;
      pk.x = cvtpk(sigm(acc[cf][mf][0]), sigm(acc[cf][mf][1]));
      pk.y = cvtpk(sigm(acc[cf][mf][2]), sigm(acc[cf][mf][3]));
      *(uint2*)((char*)gate + (m0+rr)*256 + ((c0*2) ^ ((rr&7)<<4))) = pk;
    }
  }
}

// ---------------------------------------------------------------------------
// k_proj: persistent L/R projection (unchanged).
__global__ __launch_bounds__(256, 4) void k_proj(
    const unsigned short* __restrict__ xn, const unsigned short* __restrict__ Wcat,
    const float* __restrict__ bl, const float* __restrict__ blg,
    const float* __restrict__ br, const float* __restrict__ brg,
    unsigned short* __restrict__ Lt, unsigned short* __restrict__ Rt){
  __shared__ char lds[2][16384];
  const int tid = threadIdx.x;
  const int wid = tid >> 6, lane = tid & 63;
  const int lrow = lane & 15, lgrp = lane >> 4;
  const int b = blockIdx.x;            // 1152 = 4*288
  const int f = b / 288;               // d-quarter
  const int w = b % 288;

  const int ws = wid >> 1;             // 0=L 1=R
  const int wd = wid & 1;              // d-16-half of quarter
  const int d  = f*32 + wd*16 + lrow;

  short8 bv[4], bg[4];
  #pragma unroll
  for(int ks = 0; ks < 4; ++ks){
    bv[ks] = *(const short8*)(Wcat + (ws*256 + d)*DD + ks*32 + lgrp*8);
    bg[ks] = *(const short8*)(Wcat + (ws*256 + 128 + d)*DD + ks*32 + lgrp*8);
  }
  const float b0v = (ws ? br  : bl )[d];
  const float b1v = (ws ? brg : blg)[d];
  const float sc  = ws ? 1.0f : (1.0f/384.0f);   // fold einsum 1/n into Lt
  unsigned short* const base = (ws ? Rt : Lt) + (long)d*MM;

  auto stage = [&](int buf, int v){
    int j = v/6, kb = v%6;
    int rsub = lane >> 4, c = lane & 15;
    #pragma unroll
    for(int p = 0; p < 4; ++p){
      int r0 = p*16 + wid*4;
      int r = r0 + rsub;
      gll16(xn + ((long)(kb*64 + r)*NN + j)*DD + (c ^ (r & 7))*8, &lds[buf][r0*256]);
    }
  };

  stage(0, w*8);
  __syncthreads();
  int cur = 0;
  for(int i = 0; i < 8; ++i){
    int v = w*8 + i;
    if(i < 7) stage(cur^1, v+1);       // prefetch flies over compute+epilogue

    f32x4 zero = {0.f,0.f,0.f,0.f};
    f32x4 acc[4][2];
    #pragma unroll
    for(int a1=0;a1<4;++a1){ acc[a1][0] = zero; acc[a1][1] = zero; }

    #pragma unroll
    for(int ks = 0; ks < 4; ++ks){
      #pragma unroll
      for(int fr = 0; fr < 4; ++fr){
        int r = fr*16 + lrow;
        short8 af = *(const short8*)(&lds[cur][r*256 + (((ks*4+lgrp)*16) ^ ((r&7)<<4))]);
        acc[fr][0] = mfma16(af, bv[ks], acc[fr][0]);
        acc[fr][1] = mfma16(af, bg[ks], acc[fr][1]);
      }
    }

    int j = v/6, kb = v%6;
    unsigned short* dst = base + (long)j*NN + kb*64;
    #pragma unroll
    for(int fr = 0; fr < 4; ++fr){
      float v0 = (acc[fr][0][0] + b0v)*sigm(acc[fr][1][0] + b1v)*sc;
      float v1 = (acc[fr][0][1] + b0v)*sigm(acc[fr][1][1] + b1v)*sc;
      float v2 = (acc[fr][0][2] + b0v)*sigm(acc[fr][1][2] + b1v)*sc;
      float v3 = (acc[fr][0][3] + b0v)*sigm(acc[fr][1][3] + b1v)*sc;
      uint2 pk; pk.x = cvtpk(v0, v1); pk.y = cvtpk(v2, v3);
      *(uint2*)(dst + fr*16 + lgrp*4) = pk;
    }
    __syncthreads();                   // prefetch landed; buffers swap
    cur ^= 1;
  }
}

// ---------------------------------------------------------------------------
// k_einsum: unchanged.
__global__ __launch_bounds__(256) void k_einsum(
    const unsigned short* __restrict__ Rt, const unsigned short* __restrict__ Lt,
    unsigned short* __restrict__ mid){
  __shared__ char lds[65536];
  const int b = blockIdx.x;              // 1152 = 8 * 144
  const int xcd = b & 7, slot = b >> 3;
  const int d = (slot/9)*8 + xcd;
  const int t = slot % 9;
  const int it = t/3, jt = t%3;
  const int i0 = it*128, j0 = jt*128;
  const unsigned short* Abase = Lt + (long)d*MM;   // j-rows
  const unsigned short* Bbase = Rt + (long)d*MM;   // i-rows
  const int wid = threadIdx.x >> 6, lane = threadIdx.x & 63;
  const int wr = wid >> 1, wc = wid & 1;
  const int lrow = lane & 15, lgrp = lane >> 4;

  auto stage = [&](int buf, int kt){
    int k = kt*64;
    int c = lane & 7;
    #pragma unroll
    for(int t8 = 0; t8 < 8; ++t8){
      int rr = wid*64 + t8*8 + (lane >> 3);   // 0..255 (first 128 = A rows)
      int r = rr & 127;
      const unsigned short* src = (rr < 128) ? (Abase + (long)(j0+r)*NN + k)
                                             : (Bbase + (long)(i0+r)*NN + k);
      gll16(src + (c ^ (r & 7))*8, &lds[buf*32768 + (wid*64 + t8*8)*128]);
    }
  };

  f32x4 zero = {0.f,0.f,0.f,0.f};
  f32x4 acc[4][4];                       // [fj][fi]
  #pragma unroll
  for(int a1 = 0; a1 < 4; ++a1)
    #pragma unroll
    for(int a2 = 0; a2 < 4; ++a2) acc[a1][a2] = zero;

  stage(0, 0);
  __syncthreads();
  for(int kt = 0; kt < 6; ++kt){
    int cur = kt & 1;
    if(kt < 5) stage(cur ^ 1, kt + 1);
    const int base = cur*32768;
    #pragma unroll
    for(int ks = 0; ks < 2; ++ks){
      short8 af[4], bf[4];
      #pragma unroll
      for(int f = 0; f < 4; ++f){
        int rj = wr*64 + f*16 + lrow;
        af[f] = *(const short8*)(&lds[base + rj*128 + (((ks*4+lgrp)*16) ^ ((rj & 7) << 4))]);
        int ri = wc*64 + f*16 + lrow;
        bf[f] = *(const short8*)(&lds[base + 16384 + ri*128 + (((ks*4+lgrp)*16) ^ ((ri & 7) << 4))]);
      }
      #pragma unroll
      for(int fj = 0; fj < 4; ++fj)
        #pragma unroll
        for(int fi = 0; fi < 4; ++fi)
          acc[fj][fi] = mfma16(af[fj], bf[fi], acc[fj][fi]);
    }
    __syncthreads();
  }

  #pragma unroll
  for(int fj = 0; fj < 4; ++fj){
    int j = j0 + wr*64 + fj*16 + lgrp*4;
    #pragma unroll
    for(int fi = 0; fi < 4; ++fi){
      int i = i0 + wc*64 + fi*16 + lrow;
      uint2 pk;
      pk.x = cvtpk(acc[fj][fi][0], acc[fj][fi][1]);
      pk.y = cvtpk(acc[fj][fi][2], acc[fj][fi][3]);
      *(uint2*)(mid + (long)d*MM + (long)i*NN + j) = pk;
    }
  }
}

// ---------------------------------------------------------------------------
// k_final v6: per (i, 64-wide j strip), 2 barriers.
//  Stage gate strip via gll16 (content pre-swizzled by k_lng) + gather mid
//  into midt; LN + gate-mul (val overwrites gate in place); out MFMA
//  (A=val rows -> D rows=j) with 64B-coalesced 4B stores.
__global__ __launch_bounds__(256, 4) void k_final(
    const unsigned short* __restrict__ mid, const unsigned short* __restrict__ gate,
    const float* __restrict__ ona, const float* __restrict__ onb,
    const unsigned short* __restrict__ Wot, const float* __restrict__ bo,
    float* __restrict__ out){
  __shared__ unsigned short midt[64][136];   // 17.4KB
  __shared__ char gv[16384];                 // gate -> val (in place)
  const int tid = threadIdx.x;
  const int wid = tid >> 6, lane = tid & 63;
  const int lrow = lane & 15, lgrp = lane >> 4;
  const int i = blockIdx.y;
  const int j0 = blockIdx.x*64;

  { // stage gate strip: 64 rows x 256B contiguous, linear (pre-swizzled data)
    const char* gsrc = (const char*)gate + ((long)i*NN + j0)*256;
    #pragma unroll
    for(int p = 0; p < 4; ++p)
      gll16(gsrc + p*4096 + wid*1024 + lane*16, &gv[p*4096 + wid*1024]);
  }
  { // gather mid: 128B segments per d
    int jp = tid & 15, dr = tid >> 4;
    #pragma unroll
    for(int pass = 0; pass < 8; ++pass){
      int dd = pass*16 + dr;
      uint2 v = *(const uint2*)(mid + (long)dd*MM + (long)i*NN + j0 + jp*4);
      midt[jp*4+0][dd] = (unsigned short)(v.x & 0xffffu);
      midt[jp*4+1][dd] = (unsigned short)(v.x >> 16);
      midt[jp*4+2][dd] = (unsigned short)(v.y & 0xffffu);
      midt[jp*4+3][dd] = (unsigned short)(v.y >> 16);
    }
  }
  __syncthreads();                           // B1 (drains gll16 + midt)

  { // LN + gate-mul, 4 threads per j-row; val overwrites gate in place
    int j = tid >> 2, s = tid & 3;
    float vals[32];
    float sum = 0.f, sq = 0.f;
    #pragma unroll
    for(int o8 = 0; o8 < 4; ++o8){
      short8 h = *(const short8*)(&midt[j][s*32 + o8*8]);
      #pragma unroll
      for(int q = 0; q < 8; ++q){
        float vq = bf2f((unsigned short)h[q]);
        vals[o8*8+q] = vq; sum += vq; sq += vq*vq;
      }
    }
    #pragma unroll
    for(int m = 1; m < 4; m <<= 1){ sum += __shfl_xor(sum, m); sq += __shfl_xor(sq, m); }
    float mean = sum*(1.f/128.f);
    float var  = sq *(1.f/128.f) - mean*mean;
    float rstd = rsqrtf(var + 1e-5f);
    #pragma unroll
    for(int o = 0; o < 32; o += 4){
      int dd = s*32 + o;
      char* gp = &gv[j*256 + ((dd*2) ^ ((j&7)<<4))];
      uint2 gvv = *(uint2*)gp;
      float g0 = bf2f((unsigned short)(gvv.x & 0xffffu));
      float g1 = bf2f((unsigned short)(gvv.x >> 16));
      float g2 = bf2f((unsigned short)(gvv.y & 0xffffu));
      float g3 = bf2f((unsigned short)(gvv.y >> 16));
      float4 a4 = *(const float4*)(ona + dd);
      float4 b4 = *(const float4*)(onb + dd);
      float v0 = (a4.x*(vals[o]  -mean)*rstd + b4.x)*g0;
      float v1 = (a4.y*(vals[o+1]-mean)*rstd + b4.y)*g1;
      float v2 = (a4.z*(vals[o+2]-mean)*rstd + b4.z)*g2;
      float v3 = (a4.w*(vals[o+3]-mean)*rstd + b4.w)*g3;
      uint2 pk; pk.x = cvtpk(v0, v1); pk.y = cvtpk(v2, v3);
      *(uint2*)gp = pk;                      // same thread RW: safe
    }
  }
  __syncthreads();                           // B2: val ready

  { // out MFMA: each wave = 16 j-rows x all 128 c; 4B stores, 64B segments
    f32x4 zero = {0.f,0.f,0.f,0.f};
    f32x4 acc[8];
    #pragma unroll
    for(int fc = 0; fc < 8; ++fc) acc[fc] = zero;
    #pragma unroll 1
    for(int ks = 0; ks < 4; ++ks){
      int row = wid*16 + lrow;
      short8 a = *(const short8*)(&gv[row*256 + (((ks*4+lgrp)*16) ^ ((row & 7) << 4))]);
      #pragma unroll
      for(int fc = 0; fc < 8; ++fc){
        short8 bfr = *(const short8*)(Wot + (fc*16 + lrow)*DD + ks*32 + lgrp*8);
        acc[fc] = mfma16(a, bfr, acc[fc]);
      }
    }
    #pragma unroll
    for(int fc = 0; fc < 8; ++fc){
      int c = fc*16 + lrow;
      float bb = bo[c];
      #pragma unroll
      for(int q = 0; q < 4; ++q){
        int jl = wid*16 + lgrp*4 + q;
        out[((long)i*NN + j0 + jl)*DD + c] = acc[fc][q] + bb;
      }
    }
  }
}

// ---------------------------------------------------------------------------
extern "C" void kernel_launch(void* const* d_in, const int* in_sizes, int n_in,
                              void* d_out, int out_size, void* d_ws, size_t ws_size,
                              hipStream_t stream){
  const float* x   = (const float*)d_in[0];
  const float* na  = (const float*)d_in[1];
  const float* nb  = (const float*)d_in[2];
  const float* Wl  = (const float*)d_in[3];
  const float* bl  = (const float*)d_in[4];
  const float* Wr  = (const float*)d_in[5];
  const float* br  = (const float*)d_in[6];
  const float* Wlg = (const float*)d_in[7];
  const float* blg = (const float*)d_in[8];
  const float* Wrg = (const float*)d_in[9];
  const float* brg = (const float*)d_in[10];
  const float* Wog = (const float*)d_in[11];
  const float* bog = (const float*)d_in[12];
  const float* ona = (const float*)d_in[13];
  const float* onb = (const float*)d_in[14];
  const float* Wo  = (const float*)d_in[15];
  const float* bo  = (const float*)d_in[16];
  float* out = (float*)d_out;

  char* ws = (char*)d_ws;
  const size_t SZ = (size_t)MM*DD*2;                    // 37.75 MB
  unsigned short* xn   = (unsigned short*)(ws);         // dead after k_proj
  unsigned short* Lt   = (unsigned short*)(ws + SZ);
  unsigned short* Rt   = (unsigned short*)(ws + 2*SZ);
  unsigned short* gate = (unsigned short*)(ws + 3*SZ);  // k_lng -> k_final
  unsigned short* Wcat = (unsigned short*)(ws + 4*SZ);
  unsigned short* Wot  = (unsigned short*)(ws + 4*SZ + (size_t)640*128*2);
  unsigned short* mid  = xn;                            // overlay (xn dead)

  k_prep  <<<768, 64, 0, stream>>>(Wl, Wlg, Wr, Wrg, Wog, Wo, Wcat, Wot);
  k_lng   <<<1152, 256, 0, stream>>>(x, na, nb, Wcat, bog, xn, gate);
  k_proj  <<<1152, 256, 0, stream>>>(xn, Wcat, bl, blg, br, brg, Lt, Rt);
  k_einsum<<<1152, 256, 0, stream>>>(Rt, Lt, mid);
  k_final <<<dim3(6, 384), 256, 0, stream>>>(mid, gate, ona, onb, Wot, bo, out);
}

// Round 11
// 203.931 us; speedup vs baseline: 1.3550x; 1.0367x over previous
//
#include <hip/hip_runtime.h>
#include <hip/hip_bf16.h>

#define NN 384
#define DD 128
#define MM (NN*NN)   // 147456 rows
#define IDJ 49152    // DD*NN: i-stride of mid[i][d][j]

typedef __attribute__((ext_vector_type(8))) short short8;
typedef __attribute__((ext_vector_type(4))) float f32x4;

__device__ __forceinline__ unsigned short f2bf(float f){
  unsigned u = __float_as_uint(f);
  u += 0x7fffu + ((u >> 16) & 1u);      // RNE
  return (unsigned short)(u >> 16);
}
__device__ __forceinline__ float bf2f(unsigned short u){
  return __uint_as_float(((unsigned)u) << 16);
}
__device__ __forceinline__ float sigm(float x){
  return 1.0f / (1.0f + __expf(-x));
}
__device__ __forceinline__ unsigned cvtpk(float lo, float hi){
  unsigned r;
  asm("v_cvt_pk_bf16_f32 %0, %1, %2" : "=v"(r) : "v"(lo), "v"(hi));
  return r;
}
__device__ __forceinline__ f32x4 mfma16(short8 a, short8 b, f32x4 c){
  return __builtin_amdgcn_mfma_f32_16x16x32_bf16(a, b, c, 0, 0, 0);
}
// async global->LDS, 16B/lane; LDS base wave-uniform (HW adds lane*16)
__device__ __forceinline__ void gll16(const void* g, void* l){
  __builtin_amdgcn_global_load_lds(
      (const __attribute__((address_space(1))) unsigned int*)g,
      (__attribute__((address_space(3))) unsigned int*)l, 16, 0, 0);
}

// ---------------------------------------------------------------------------
// k_prep: Wcat_t[n][k] bf16 = [Wl|Wlg|Wr|Wrg|Wog]^T (n in [0,640)); Wot = Wo^T.
__global__ void k_prep(const float* __restrict__ Wl, const float* __restrict__ Wlg,
                       const float* __restrict__ Wr, const float* __restrict__ Wrg,
                       const float* __restrict__ Wog, const float* __restrict__ Wo,
                       unsigned short* __restrict__ Wcat, unsigned short* __restrict__ Wot){
  int n = blockIdx.x;           // 0..767
  if(n < 640){
    const float* src; int col;
    if(n < 128){ src = Wl;  col = n; }
    else if(n < 256){ src = Wlg; col = n-128; }
    else if(n < 384){ src = Wr;  col = n-256; }
    else if(n < 512){ src = Wrg; col = n-384; }
    else            { src = Wog; col = n-512; }
    for(int k = threadIdx.x; k < 128; k += 64)
      Wcat[n*128 + k] = f2bf(src[k*128 + col]);
  } else {
    int c = n - 640;
    for(int k = threadIdx.x; k < 128; k += 64)
      Wot[c*128 + k] = f2bf(Wo[k*128 + c]);
  }
}

// ---------------------------------------------------------------------------
// k_lng: fused LayerNorm(x) -> xn  AND  gate = sigm(xn @ Wog + bog).
//  LN loop batched 4-wide for memory-level parallelism (4 row-loads in
//  flight before the 4 independent shuffle reductions).
__global__ __launch_bounds__(256, 3) void k_lng(
    const float* __restrict__ x, const float* __restrict__ na,
    const float* __restrict__ nb, const unsigned short* __restrict__ Wcat,
    const float* __restrict__ bog,
    unsigned short* __restrict__ xn, unsigned short* __restrict__ gate){
  __shared__ char lds[32768];            // xn tile [128 rows][256B], swizzled
  const int tid = threadIdx.x;
  const int wid = tid >> 6, lane = tid & 63;
  const int lrow = lane & 15, lgrp = lane >> 4;
  const long m0 = (long)blockIdx.x * 128;

  float2 a2 = *(const float2*)(na + lane*2);
  float2 b2 = *(const float2*)(nb + lane*2);

  #pragma unroll 2
  for(int b4 = 0; b4 < 8; ++b4){
    float2 v[4];
    #pragma unroll
    for(int s = 0; s < 4; ++s)
      v[s] = *(const float2*)(x + (m0 + wid*32 + b4*4 + s)*DD + lane*2);
    #pragma unroll
    for(int s = 0; s < 4; ++s){
      int r = wid*32 + b4*4 + s;
      float sm = v[s].x + v[s].y, sq = v[s].x*v[s].x + v[s].y*v[s].y;
      #pragma unroll
      for(int m = 32; m >= 1; m >>= 1){ sm += __shfl_xor(sm,m); sq += __shfl_xor(sq,m); }
      float mean = sm*(1.f/128.f);
      float var  = sq*(1.f/128.f) - mean*mean;
      float rstd = rsqrtf(var + 1e-5f);
      unsigned pk = cvtpk(a2.x*(v[s].x-mean)*rstd + b2.x,
                          a2.y*(v[s].y-mean)*rstd + b2.y);
      *(unsigned*)(xn + (m0+r)*DD + lane*2) = pk;
      *(unsigned*)(&lds[r*256 + ((lane*4) ^ ((r&7)<<4))]) = pk;
    }
  }
  __syncthreads();

  // gate MFMA: wave wid owns 32 c-cols
  f32x4 acc[2][8];                       // [cf][mf]
  #pragma unroll
  for(int cf = 0; cf < 2; ++cf){
    int c0 = wid*32 + cf*16 + lgrp*4;
    float4 b4v = *(const float4*)(bog + c0);
    #pragma unroll
    for(int mf = 0; mf < 8; ++mf) acc[cf][mf] = (f32x4){b4v.x,b4v.y,b4v.z,b4v.w};
  }
  #pragma unroll
  for(int ks = 0; ks < 4; ++ks){
    short8 af0 = *(const short8*)(Wcat + (512 + wid*32 + lrow)*DD + ks*32 + lgrp*8);
    short8 af1 = *(const short8*)(Wcat + (512 + wid*32 + 16 + lrow)*DD + ks*32 + lgrp*8);
    #pragma unroll
    for(int mf = 0; mf < 8; ++mf){
      int r = mf*16 + lrow;
      short8 bx = *(const short8*)(&lds[r*256 + (((ks*4+lgrp)*16) ^ ((r&7)<<4))]);
      acc[0][mf] = mfma16(af0, bx, acc[0][mf]);
      acc[1][mf] = mfma16(af1, bx, acc[1][mf]);
    }
  }
  // packed 8B stores, pre-swizzled within the 256B row
  #pragma unroll
  for(int cf = 0; cf < 2; ++cf){
    int c0 = wid*32 + cf*16 + lgrp*4;
    #pragma unroll
    for(int mf = 0; mf < 8; ++mf){
      int rr = mf*16 + lrow;
      uint2 pk;
      pk.x = cvtpk(sigm(acc[cf][mf][0]), sigm(acc[cf][mf][1]));
      pk.y = cvtpk(sigm(acc[cf][mf][2]), sigm(acc[cf][mf][3]));
      *(uint2*)((char*)gate + (m0+rr)*256 + ((c0*2) ^ ((rr&7)<<4))) = pk;
    }
  }
}

// ---------------------------------------------------------------------------
// k_proj: persistent L/R projection (unchanged).
__global__ __launch_bounds__(256, 4) void k_proj(
    const unsigned short* __restrict__ xn, const unsigned short* __restrict__ Wcat,
    const float* __restrict__ bl, const float* __restrict__ blg,
    const float* __restrict__ br, const float* __restrict__ brg,
    unsigned short* __restrict__ Lt, unsigned short* __restrict__ Rt){
  __shared__ char lds[2][16384];
  const int tid = threadIdx.x;
  const int wid = tid >> 6, lane = tid & 63;
  const int lrow = lane & 15, lgrp = lane >> 4;
  const int b = blockIdx.x;            // 1152 = 4*288
  const int f = b / 288;               // d-quarter
  const int w = b % 288;

  const int ws = wid >> 1;             // 0=L 1=R
  const int wd = wid & 1;              // d-16-half of quarter
  const int d  = f*32 + wd*16 + lrow;

  short8 bv[4], bg[4];
  #pragma unroll
  for(int ks = 0; ks < 4; ++ks){
    bv[ks] = *(const short8*)(Wcat + (ws*256 + d)*DD + ks*32 + lgrp*8);
    bg[ks] = *(const short8*)(Wcat + (ws*256 + 128 + d)*DD + ks*32 + lgrp*8);
  }
  const float b0v = (ws ? br  : bl )[d];
  const float b1v = (ws ? brg : blg)[d];
  const float sc  = ws ? 1.0f : (1.0f/384.0f);   // fold einsum 1/n into Lt
  unsigned short* const base = (ws ? Rt : Lt) + (long)d*MM;

  auto stage = [&](int buf, int v){
    int j = v/6, kb = v%6;
    int rsub = lane >> 4, c = lane & 15;
    #pragma unroll
    for(int p = 0; p < 4; ++p){
      int r0 = p*16 + wid*4;
      int r = r0 + rsub;
      gll16(xn + ((long)(kb*64 + r)*NN + j)*DD + (c ^ (r & 7))*8, &lds[buf][r0*256]);
    }
  };

  stage(0, w*8);
  __syncthreads();
  int cur = 0;
  for(int i = 0; i < 8; ++i){
    int v = w*8 + i;
    if(i < 7) stage(cur^1, v+1);       // prefetch flies over compute+epilogue

    f32x4 zero = {0.f,0.f,0.f,0.f};
    f32x4 acc[4][2];
    #pragma unroll
    for(int a1=0;a1<4;++a1){ acc[a1][0] = zero; acc[a1][1] = zero; }

    #pragma unroll
    for(int ks = 0; ks < 4; ++ks){
      #pragma unroll
      for(int fr = 0; fr < 4; ++fr){
        int r = fr*16 + lrow;
        short8 af = *(const short8*)(&lds[cur][r*256 + (((ks*4+lgrp)*16) ^ ((r&7)<<4))]);
        acc[fr][0] = mfma16(af, bv[ks], acc[fr][0]);
        acc[fr][1] = mfma16(af, bg[ks], acc[fr][1]);
      }
    }

    int j = v/6, kb = v%6;
    unsigned short* dst = base + (long)j*NN + kb*64;
    #pragma unroll
    for(int fr = 0; fr < 4; ++fr){
      float v0 = (acc[fr][0][0] + b0v)*sigm(acc[fr][1][0] + b1v)*sc;
      float v1 = (acc[fr][0][1] + b0v)*sigm(acc[fr][1][1] + b1v)*sc;
      float v2 = (acc[fr][0][2] + b0v)*sigm(acc[fr][1][2] + b1v)*sc;
      float v3 = (acc[fr][0][3] + b0v)*sigm(acc[fr][1][3] + b1v)*sc;
      uint2 pk; pk.x = cvtpk(v0, v1); pk.y = cvtpk(v2, v3);
      *(uint2*)(dst + fr*16 + lgrp*4) = pk;
    }
    __syncthreads();                   // prefetch landed; buffers swap
    cur ^= 1;
  }
}

// ---------------------------------------------------------------------------
// k_einsum: per d: mid[i][d][j] = sum_k Rt[d][i][k]*Lt[d][j][k] (1/384 in Lt).
//  Output layout is now i-major so k_final reads a contiguous 98KB per i.
__global__ __launch_bounds__(256) void k_einsum(
    const unsigned short* __restrict__ Rt, const unsigned short* __restrict__ Lt,
    unsigned short* __restrict__ mid){
  __shared__ char lds[65536];
  const int b = blockIdx.x;              // 1152 = 8 * 144
  const int xcd = b & 7, slot = b >> 3;
  const int d = (slot/9)*8 + xcd;
  const int t = slot % 9;
  const int it = t/3, jt = t%3;
  const int i0 = it*128, j0 = jt*128;
  const unsigned short* Abase = Lt + (long)d*MM;   // j-rows
  const unsigned short* Bbase = Rt + (long)d*MM;   // i-rows
  const int wid = threadIdx.x >> 6, lane = threadIdx.x & 63;
  const int wr = wid >> 1, wc = wid & 1;
  const int lrow = lane & 15, lgrp = lane >> 4;

  auto stage = [&](int buf, int kt){
    int k = kt*64;
    int c = lane & 7;
    #pragma unroll
    for(int t8 = 0; t8 < 8; ++t8){
      int rr = wid*64 + t8*8 + (lane >> 3);   // 0..255 (first 128 = A rows)
      int r = rr & 127;
      const unsigned short* src = (rr < 128) ? (Abase + (long)(j0+r)*NN + k)
                                             : (Bbase + (long)(i0+r)*NN + k);
      gll16(src + (c ^ (r & 7))*8, &lds[buf*32768 + (wid*64 + t8*8)*128]);
    }
  };

  f32x4 zero = {0.f,0.f,0.f,0.f};
  f32x4 acc[4][4];                       // [fj][fi]
  #pragma unroll
  for(int a1 = 0; a1 < 4; ++a1)
    #pragma unroll
    for(int a2 = 0; a2 < 4; ++a2) acc[a1][a2] = zero;

  stage(0, 0);
  __syncthreads();
  for(int kt = 0; kt < 6; ++kt){
    int cur = kt & 1;
    if(kt < 5) stage(cur ^ 1, kt + 1);
    const int base = cur*32768;
    #pragma unroll
    for(int ks = 0; ks < 2; ++ks){
      short8 af[4], bf[4];
      #pragma unroll
      for(int f = 0; f < 4; ++f){
        int rj = wr*64 + f*16 + lrow;
        af[f] = *(const short8*)(&lds[base + rj*128 + (((ks*4+lgrp)*16) ^ ((rj & 7) << 4))]);
        int ri = wc*64 + f*16 + lrow;
        bf[f] = *(const short8*)(&lds[base + 16384 + ri*128 + (((ks*4+lgrp)*16) ^ ((ri & 7) << 4))]);
      }
      #pragma unroll
      for(int fj = 0; fj < 4; ++fj)
        #pragma unroll
        for(int fi = 0; fi < 4; ++fi)
          acc[fj][fi] = mfma16(af[fj], bf[fi], acc[fj][fi]);
    }
    __syncthreads();
  }

  #pragma unroll
  for(int fj = 0; fj < 4; ++fj){
    int j = j0 + wr*64 + fj*16 + lgrp*4;
    #pragma unroll
    for(int fi = 0; fi < 4; ++fi){
      int i = i0 + wc*64 + fi*16 + lrow;
      uint2 pk;
      pk.x = cvtpk(acc[fj][fi][0], acc[fj][fi][1]);
      pk.y = cvtpk(acc[fj][fi][2], acc[fj][fi][3]);
      *(uint2*)(mid + (long)i*IDJ + (long)d*NN + j) = pk;
    }
  }
}

// ---------------------------------------------------------------------------
// k_final v7: flat grid 2304 = 8 xcd * 288; i = xcd + 8*(slot/6) so all six
//  j-strips of one i share an XCD -> the i's contiguous 98KB mid block is
//  fetched once into that L2 and fully consumed (fixes the 485 GB/s strided
//  read). Otherwise identical to v6 (2 barriers, in-place gate->val).
__global__ __launch_bounds__(256, 4) void k_final(
    const unsigned short* __restrict__ mid, const unsigned short* __restrict__ gate,
    const float* __restrict__ ona, const float* __restrict__ onb,
    const unsigned short* __restrict__ Wot, const float* __restrict__ bo,
    float* __restrict__ out){
  __shared__ unsigned short midt[64][136];   // 17.4KB
  __shared__ char gv[16384];                 // gate -> val (in place)
  const int tid = threadIdx.x;
  const int wid = tid >> 6, lane = tid & 63;
  const int lrow = lane & 15, lgrp = lane >> 4;
  const int b = blockIdx.x;
  const int xcd = b & 7, slot = b >> 3;      // 2304 = 8*288
  const int i = xcd + (slot/6)*8;
  const int j0 = (slot%6)*64;

  { // stage gate strip: 64 rows x 256B contiguous, linear (pre-swizzled data)
    const char* gsrc = (const char*)gate + ((long)i*NN + j0)*256;
    #pragma unroll
    for(int p = 0; p < 4; ++p)
      gll16(gsrc + p*4096 + wid*1024 + lane*16, &gv[p*4096 + wid*1024]);
  }
  { // gather mid: 128B segments, ALL within i's contiguous 98KB region
    int jp = tid & 15, dr = tid >> 4;
    const unsigned short* mp = mid + (long)i*IDJ + j0 + jp*4;
    #pragma unroll
    for(int pass = 0; pass < 8; ++pass){
      int dd = pass*16 + dr;
      uint2 v = *(const uint2*)(mp + dd*NN);
      midt[jp*4+0][dd] = (unsigned short)(v.x & 0xffffu);
      midt[jp*4+1][dd] = (unsigned short)(v.x >> 16);
      midt[jp*4+2][dd] = (unsigned short)(v.y & 0xffffu);
      midt[jp*4+3][dd] = (unsigned short)(v.y >> 16);
    }
  }
  __syncthreads();                           // B1 (drains gll16 + midt)

  { // LN + gate-mul, 4 threads per j-row; val overwrites gate in place
    int j = tid >> 2, s = tid & 3;
    float vals[32];
    float sum = 0.f, sq = 0.f;
    #pragma unroll
    for(int o8 = 0; o8 < 4; ++o8){
      short8 h = *(const short8*)(&midt[j][s*32 + o8*8]);
      #pragma unroll
      for(int q = 0; q < 8; ++q){
        float vq = bf2f((unsigned short)h[q]);
        vals[o8*8+q] = vq; sum += vq; sq += vq*vq;
      }
    }
    #pragma unroll
    for(int m = 1; m < 4; m <<= 1){ sum += __shfl_xor(sum, m); sq += __shfl_xor(sq, m); }
    float mean = sum*(1.f/128.f);
    float var  = sq *(1.f/128.f) - mean*mean;
    float rstd = rsqrtf(var + 1e-5f);
    #pragma unroll
    for(int o = 0; o < 32; o += 4){
      int dd = s*32 + o;
      char* gp = &gv[j*256 + ((dd*2) ^ ((j&7)<<4))];
      uint2 gvv = *(uint2*)gp;
      float g0 = bf2f((unsigned short)(gvv.x & 0xffffu));
      float g1 = bf2f((unsigned short)(gvv.x >> 16));
      float g2 = bf2f((unsigned short)(gvv.y & 0xffffu));
      float g3 = bf2f((unsigned short)(gvv.y >> 16));
      float4 a4 = *(const float4*)(ona + dd);
      float4 b4 = *(const float4*)(onb + dd);
      float v0 = (a4.x*(vals[o]  -mean)*rstd + b4.x)*g0;
      float v1 = (a4.y*(vals[o+1]-mean)*rstd + b4.y)*g1;
      float v2 = (a4.z*(vals[o+2]-mean)*rstd + b4.z)*g2;
      float v3 = (a4.w*(vals[o+3]-mean)*rstd + b4.w)*g3;
      uint2 pk; pk.x = cvtpk(v0, v1); pk.y = cvtpk(v2, v3);
      *(uint2*)gp = pk;                      // same thread RW: safe
    }
  }
  __syncthreads();                           // B2: val ready

  { // out MFMA: each wave = 16 j-rows x all 128 c; 4B stores, 64B segments
    f32x4 zero = {0.f,0.f,0.f,0.f};
    f32x4 acc[8];
    #pragma unroll
    for(int fc = 0; fc < 8; ++fc) acc[fc] = zero;
    #pragma unroll 1
    for(int ks = 0; ks < 4; ++ks){
      int row = wid*16 + lrow;
      short8 a = *(const short8*)(&gv[row*256 + (((ks*4+lgrp)*16) ^ ((row & 7) << 4))]);
      #pragma unroll
      for(int fc = 0; fc < 8; ++fc){
        short8 bfr = *(const short8*)(Wot + (fc*16 + lrow)*DD + ks*32 + lgrp*8);
        acc[fc] = mfma16(a, bfr, acc[fc]);
      }
    }
    #pragma unroll
    for(int fc = 0; fc < 8; ++fc){
      int c = fc*16 + lrow;
      float bb = bo[c];
      #pragma unroll
      for(int q = 0; q < 4; ++q){
        int jl = wid*16 + lgrp*4 + q;
        out[((long)i*NN + j0 + jl)*DD + c] = acc[fc][q] + bb;
      }
    }
  }
}

// ---------------------------------------------------------------------------
extern "C" void kernel_launch(void* const* d_in, const int* in_sizes, int n_in,
                              void* d_out, int out_size, void* d_ws, size_t ws_size,
                              hipStream_t stream){
  const float* x   = (const float*)d_in[0];
  const float* na  = (const float*)d_in[1];
  const float* nb  = (const float*)d_in[2];
  const float* Wl  = (const float*)d_in[3];
  const float* bl  = (const float*)d_in[4];
  const float* Wr  = (const float*)d_in[5];
  const float* br  = (const float*)d_in[6];
  const float* Wlg = (const float*)d_in[7];
  const float* blg = (const float*)d_in[8];
  const float* Wrg = (const float*)d_in[9];
  const float* brg = (const float*)d_in[10];
  const float* Wog = (const float*)d_in[11];
  const float* bog = (const float*)d_in[12];
  const float* ona = (const float*)d_in[13];
  const float* onb = (const float*)d_in[14];
  const float* Wo  = (const float*)d_in[15];
  const float* bo  = (const float*)d_in[16];
  float* out = (float*)d_out;

  char* ws = (char*)d_ws;
  const size_t SZ = (size_t)MM*DD*2;                    // 37.75 MB
  unsigned short* xn   = (unsigned short*)(ws);         // dead after k_proj
  unsigned short* Lt   = (unsigned short*)(ws + SZ);
  unsigned short* Rt   = (unsigned short*)(ws + 2*SZ);
  unsigned short* gate = (unsigned short*)(ws + 3*SZ);  // k_lng -> k_final
  unsigned short* Wcat = (unsigned short*)(ws + 4*SZ);
  unsigned short* Wot  = (unsigned short*)(ws + 4*SZ + (size_t)640*128*2);
  unsigned short* mid  = xn;                            // overlay (xn dead)

  k_prep  <<<768, 64, 0, stream>>>(Wl, Wlg, Wr, Wrg, Wog, Wo, Wcat, Wot);
  k_lng   <<<1152, 256, 0, stream>>>(x, na, nb, Wcat, bog, xn, gate);
  k_proj  <<<1152, 256, 0, stream>>>(xn, Wcat, bl, blg, br, brg, Lt, Rt);
  k_einsum<<<1152, 256, 0, stream>>>(Rt, Lt, mid);
  k_final <<<2304, 256, 0, stream>>>(mid, gate, ona, onb, Wot, bo, out);
}